// Round 11
// baseline (299.694 us; speedup 1.0000x reference)
//
#include <hip/hip_runtime.h>
#include <stdint.h>
#include <stddef.h>

#define BATCH 16
#define SEQ 2048
#define HDIM 256
#define SCHUNK 32
#define TTILE 128
#define NCHUNK 64            // SEQ / SCHUNK
#define TILE_U16 8192        // 16 KB tile (32 x 256 halves)
#define NTILES 1024          // BATCH * NCHUNK
#define KSTRIDE 260          // prepass fp32 staging row stride (bank stride 4)

typedef float f32x4 __attribute__((ext_vector_type(4)));
typedef float f32x16 __attribute__((ext_vector_type(16)));
typedef _Float16 f16x8 __attribute__((ext_vector_type(8)));
typedef __bf16 bf16x8 __attribute__((ext_vector_type(8)));
typedef unsigned short u16;
typedef u16 u16x8 __attribute__((ext_vector_type(8)));
typedef unsigned int u32;
typedef u32 u32x4 __attribute__((ext_vector_type(4)));
typedef const __attribute__((address_space(1))) u32* gp1_t;
typedef __attribute__((address_space(3))) u32* lp3_t;

// Monotonic grid barrier counter. Never reset: each launch's 256 arrivals
// push it to the next multiple of 256, so replays (graph / rocprof) work.
__device__ unsigned int g_bar = 0;

static __device__ __forceinline__ u16 f2bf(float f) {
  union { float f; unsigned int u; } v; v.f = f;
  unsigned int u = v.u;
  unsigned int r = u + 0x7FFFu + ((u >> 16) & 1u);  // RNE
  return (u16)(r >> 16);
}

// ============================================================================
// FUSED kernel (r11): ONE dispatch = prepass phase + grid barrier + r3 attn.
//
// Phase 1: block (b, t) builds fragment tiles for chunks [4t, 4t+4) of ITS
//   batch b (exact cover of all 1024 (b,ck) tiles). Scratch Ks (33 KB fp32)
//   aliases KHs. All 16 blocks of a batch live on ONE XCD (bid mod 16 fixes
//   bid mod 8), so phase-1 writes are read back same-XCD (L2-coherent).
// Barrier: monotonic device-scope atomic barrier; co-residency guaranteed
//   (160 KB LDS -> 1 block/CU, grid = 256 = #CU).
// Phase 2: the round-3 champion attention, verbatim (92.5 µs measured).
// ============================================================================
__global__ __launch_bounds__(512, 2)
void attn_fused_kernel(const float* __restrict__ e,
                       u16* __restrict__ KH, u16* __restrict__ VT,
                       const float* __restrict__ dq,  // [T, B, H]
                       float* __restrict__ out) {     // [T, B, H]
  __shared__ alignas(16) u16 KHs[4][TILE_U16];   // 64 KB : K pair-sets (phase-1 scratch)
  __shared__ alignas(16) u16 VTs[6][TILE_U16];   // 96 KB : V pair-sets

  const int tid  = threadIdx.x;
  const int lane = tid & 63;
  const int wv   = tid >> 6;        // 0..7
  const int wq   = wv & 3;          // target-group 0..3
  const int grp  = wv >> 2;         // 0 = even chunks, 1 = odd chunks
  const int m    = lane & 31;
  const int g    = lane >> 5;

  // XCD-aware swizzle: XCD x gets batches {2x, 2x+1} (4 MB ~= L2).
  const int bid  = blockIdx.x;
  const int b    = ((bid & 7) << 1) | ((bid >> 3) & 1);
  const int tq16 = bid >> 4;        // t-tile index 0..15
  const int t0   = tq16 * TTILE;

  // ======================= PHASE 1: prepass =======================
  {
    float* Ks = (float*)&KHs[0][0];       // 32 x 260 fp32 = 33,280 B scratch
    for (int cc = 0; cc < 4; ++cc) {
      const int ck = tq16 * 4 + cc;       // my 4 chunks of batch b
      const size_t tile = ((size_t)b * NCHUNK + ck) * TILE_U16;

      { // load 32 rows of e, sum the two directions -> Ks
        int row = tid >> 4;               // 0..31
        int c16 = tid & 15;               // 0..15
        const float* src = e + ((size_t)(ck * SCHUNK + row) * BATCH + b) * (2 * HDIM);
#pragma unroll
        for (int u = 0; u < 4; ++u) {
          int col = c16 * 4 + 64 * u;
          float4 xa = *(const float4*)(src + col);
          float4 xb = *(const float4*)(src + col + HDIM);
          float4 s; s.x = xa.x + xb.x; s.y = xa.y + xb.y;
          s.z = xa.z + xb.z; s.w = xa.w + xb.w;
          *(float4*)&Ks[row * KSTRIDE + col] = s;
        }
      }
      __syncthreads();

      // KH (fp16 QK A-op): wave wv covers kb = 2*wv + i
#pragma unroll
      for (int i = 0; i < 2; ++i) {
        int kb = wv * 2 + i;
        const float* rp = &Ks[m * KSTRIDE + kb * 16 + g * 8];
        u16x8 hi;
#pragma unroll
        for (int j = 0; j < 8; ++j)
          hi[j] = __builtin_bit_cast(u16, (_Float16)rp[j]);
        *(u16x8*)&KH[tile + (size_t)(kb * 64 + lane) * 8] = hi;
      }
      // VT (bf16 PV B-op, transposed): wave wv covers fr = 2*wv + i
#pragma unroll
      for (int i = 0; i < 2; ++i) {
        int fr = wv * 2 + i;
        int ht = fr >> 1, ka = fr & 1;
        u16x8 v;
#pragma unroll
        for (int j = 0; j < 8; ++j)
          v[j] = f2bf(Ks[(ka * 16 + g * 8 + j) * KSTRIDE + ht * 32 + m]);
        *(u16x8*)&VT[tile + (size_t)(fr * 64 + lane) * 8] = v;
      }
      __syncthreads();                    // Ks reads done before next overwrite
    }
  }

  // ======================= grid barrier =======================
  __threadfence();                        // release phase-1 global writes
  __syncthreads();
  if (tid == 0) {
    unsigned int old = __hip_atomic_fetch_add(&g_bar, 1u, __ATOMIC_ACQ_REL,
                                              __HIP_MEMORY_SCOPE_AGENT);
    unsigned int target = ((old >> 8) + 1u) << 8;   // next multiple of 256
    while (__hip_atomic_load(&g_bar, __ATOMIC_ACQUIRE,
                             __HIP_MEMORY_SCOPE_AGENT) < target)
      __builtin_amdgcn_s_sleep(8);
  }
  __syncthreads();

  // ======================= PHASE 2: r3 attention (verbatim) =======================
  // ---- Q fragments fp16 (B-operand: B[k=g*8+j][n=m]) ----
  const int tq = t0 + wq * 32 + m;
  const float* qp = dq + ((size_t)tq * BATCH + b) * HDIM;
  f16x8 qh[16];
#pragma unroll
  for (int kb = 0; kb < 16; ++kb) {
    int h = kb * 16 + g * 8;
    float4 f0 = *(const float4*)(qp + h);
    float4 f1 = *(const float4*)(qp + h + 4);
    float xs[8] = {f0.x, f0.y, f0.z, f0.w, f1.x, f1.y, f1.z, f1.w};
    u16x8 hb;
#pragma unroll
    for (int j = 0; j < 8; ++j)
      hb[j] = __builtin_bit_cast(u16, (_Float16)xs[j]);
    qh[kb] = __builtin_bit_cast(f16x8, hb);
  }

  f32x16 ctx[8];
#pragma unroll
  for (int ht = 0; ht < 8; ++ht) ctx[ht] = (f32x16)(0.0f);
  float dsum = 0.0f;
  bf16x8 pa0 = {}, pa1 = {};     // P fragments for the pending PV (registers)

  // ---- staging: wave wv owns 8 KB of a pair's 32 KB stage ----
  const bool isVT  = (wv >> 1) & 1;
  const int  choff = wv >> 2;
  const int  subbase = (wv & 1) * 8;
  const u16* srcArr = isVT ? VT : KH;
  auto stage = [&](int p) {                 // stage pair p
    int ckk = 2 * p + choff;
    int ktile = 2 * (p & 1) + choff;        // K: 2 pair-sets
    int vtile = (p % 3) * 2 + choff;        // V: 3 pair-sets
    size_t tb = ((size_t)b * NCHUNK + ckk) * TILE_U16;
    u16* dst = isVT ? &VTs[vtile][0] : &KHs[ktile][0];
#pragma unroll
    for (int i = 0; i < 8; ++i) {
      int sub = subbase + i;
      __builtin_amdgcn_global_load_lds(
          (gp1_t)(const void*)&srcArr[tb + (size_t)sub * 512 + lane * 8],
          (lp3_t)(void*)&dst[sub * 512], 16, 0, 0);
    }
  };

  // QK^T as S^T (m=s, n=t) for pair p, fp16, two independent chains
  auto qk = [&](int p, f32x16& a0, f32x16& a1) {
    int kt = 2 * (p & 1) + grp;
#pragma unroll
    for (int kb = 0; kb < 16; kb += 2) {
      f16x8 k0 = __builtin_bit_cast(f16x8, *(const u16x8*)&KHs[kt][kb * 512 + lane * 8]);
      f16x8 k1 = __builtin_bit_cast(f16x8, *(const u16x8*)&KHs[kt][(kb + 1) * 512 + lane * 8]);
      a0 = __builtin_amdgcn_mfma_f32_32x32x16_f16(k0, qh[kb], a0, 0, 0, 0);
      a1 = __builtin_amdgcn_mfma_f32_32x32x16_f16(k1, qh[kb + 1], a1, 0, 0, 0);
    }
  };

  // PV for pair p using register P fragments pa0/pa1
  auto pv = [&](int p) {
    int vt_ = (p % 3) * 2 + grp;
#pragma unroll
    for (int ht = 0; ht < 8; ++ht) {
      bf16x8 v0 = __builtin_bit_cast(bf16x8, *(const u16x8*)&VTs[vt_][(ht * 2) * 512 + lane * 8]);
      bf16x8 v1 = __builtin_bit_cast(bf16x8, *(const u16x8*)&VTs[vt_][(ht * 2 + 1) * 512 + lane * 8]);
      ctx[ht] = __builtin_amdgcn_mfma_f32_32x32x16_bf16(pa0, v0, ctx[ht], 0, 0, 0);
      ctx[ht] = __builtin_amdgcn_mfma_f32_32x32x16_bf16(pa1, v1, ctx[ht], 0, 0, 0);
    }
  };

  // exp(s-128) -> dsum; cvt_pk + permlane32_swap builds PV A-frags (T12).
  auto softmax_pack = [&](const f32x16& a0, const f32x16& a1) {
    float pf[16];
#pragma unroll
    for (int r = 0; r < 16; ++r) {
      pf[r] = __expf(a0[r] + a1[r] - 128.0f);
      dsum += pf[r];
    }
    u32 c[8];
#pragma unroll
    for (int q = 0; q < 8; ++q)
      asm("v_cvt_pk_bf16_f32 %0, %1, %2"
          : "=v"(c[q]) : "v"(pf[2 * q]), "v"(pf[2 * q + 1]));
    asm("v_permlane32_swap_b32 %0, %1" : "+v"(c[0]), "+v"(c[2]));
    asm("v_permlane32_swap_b32 %0, %1" : "+v"(c[1]), "+v"(c[3]));
    asm("v_permlane32_swap_b32 %0, %1" : "+v"(c[4]), "+v"(c[6]));
    asm("v_permlane32_swap_b32 %0, %1" : "+v"(c[5]), "+v"(c[7]));
    u32x4 w0 = {c[0], c[1], c[2], c[3]};
    u32x4 w1 = {c[4], c[5], c[6], c[7]};
    pa0 = __builtin_bit_cast(bf16x8, w0);
    pa1 = __builtin_bit_cast(bf16x8, w1);
  };

  // ---- prologue: stage pairs 0,1; QK_0 + SM_0 ----
  stage(0);
  stage(1);
  asm volatile("s_waitcnt vmcnt(8)" ::: "memory");  // pair 0 landed; pair 1 in flight
  __builtin_amdgcn_s_barrier();
  {
    f32x16 a0 = (f32x16)(0.0f), a1 = (f32x16)(0.0f);
    qk(0, a0, a1);
    softmax_pack(a0, a1);
  }

  // ---- main loop: QK_{j+1} || PV_j, one barrier per iter ----
  for (int j = 0; j < 32; ++j) {
    asm volatile("s_waitcnt vmcnt(0)" ::: "memory"); // stage(j+1) landed
    __builtin_amdgcn_s_barrier();
    if (j < 30) stage(j + 2);

    f32x16 a0 = (f32x16)(0.0f), a1 = (f32x16)(0.0f);
    __builtin_amdgcn_s_setprio(1);
    if (j < 31) qk(j + 1, a0, a1);   // independent of PV below
    pv(j);                           // consumes pa0/pa1 from previous SM
    __builtin_amdgcn_s_setprio(0);
    if (j < 31) softmax_pack(a0, a1);  // overlaps in-flight PV MFMAs
  }

  // ---- combine the two source-halves (exact: same exp offset) ----
  dsum += __shfl_xor(dsum, 32, 64);   // per-lane: partial denom for t = m
  __syncthreads();                     // full drain once; bufs reusable

  // exchange regions (32 KB per target-group) carved from KHs/VTs
  float* exch = (wq == 0) ? (float*)&KHs[0][0]
              : (wq == 1) ? (float*)&KHs[2][0]
              : (wq == 2) ? (float*)&VTs[0][0]
                          : (float*)&VTs[2][0];
  float* dex = (float*)&VTs[4][0];   // denom exchange (1 KB)

  if (grp == 1) {
    // layout [r4][ht][lane][4]: b128, 2-way banks (free)
#pragma unroll
    for (int r4 = 0; r4 < 4; ++r4)
#pragma unroll
      for (int ht = 0; ht < 8; ++ht) {
        f32x4 v = {ctx[ht][r4 * 4], ctx[ht][r4 * 4 + 1],
                   ctx[ht][r4 * 4 + 2], ctx[ht][r4 * 4 + 3]};
        *(f32x4*)&exch[r4 * 2048 + ht * 256 + lane * 4] = v;
      }
    dex[wq * 64 + lane] = dsum;
  }
  __syncthreads();

  if (grp == 0) {
    float dB = dex[wq * 64 + lane];
    float inv = 1.0f / (dsum + dB);
#pragma unroll
    for (int r4 = 0; r4 < 4; ++r4)
#pragma unroll
      for (int ht = 0; ht < 8; ++ht) {
        f32x4 v = *(const f32x4*)&exch[r4 * 2048 + ht * 256 + lane * 4];
        ctx[ht][r4 * 4]     += v[0];
        ctx[ht][r4 * 4 + 1] += v[1];
        ctx[ht][r4 * 4 + 2] += v[2];
        ctx[ht][r4 * 4 + 3] += v[3];
      }
#pragma unroll
    for (int r = 0; r < 16; ++r) {
      int tl = (r & 3) + 8 * (r >> 2) + 4 * g;
      float rinv = __shfl(inv, tl, 64);
      int t = t0 + wq * 32 + tl;
      float* op = out + ((size_t)t * BATCH + b) * HDIM + m;
#pragma unroll
      for (int ht = 0; ht < 8; ++ht)
        op[ht * 32] = ctx[ht][r] * rinv;
    }
  }
}

extern "C" void kernel_launch(void* const* d_in, const int* in_sizes, int n_in,
                              void* d_out, int out_size, void* d_ws, size_t ws_size,
                              hipStream_t stream) {
  const float* e  = (const float*)d_in[0];  // out_e [2048, 16, 512]
  const float* dq = (const float*)d_in[1];  // out_d [2048, 16, 256]
  float* out = (float*)d_out;               // [2048, 16, 256]
  u16* KH = (u16*)d_ws;                                 // fp16 bits, 16 MB
  u16* VT = KH + (size_t)NTILES * TILE_U16;             // bf16 bits, 16 MB
  attn_fused_kernel<<<dim3(BATCH * (SEQ / TTILE)), dim3(512), 0, stream>>>(
      e, KH, VT, dq, out);
}